// Round 16
// baseline (234.965 us; speedup 1.0000x reference)
//
#include <hip/hip_runtime.h>
#include <hip/hip_bf16.h>
#include <stdint.h>

#define D_IN 1024
#define D_K  128
#define NBATCH 8
#define SEQ  4096
#define MROWS (NBATCH * SEQ)

typedef __attribute__((ext_vector_type(8))) short bf16x8;
typedef __attribute__((ext_vector_type(4))) float f32x4;

__device__ __forceinline__ unsigned short f32_to_bf16(float x) {
    union { float f; uint32_t u; } v; v.f = x;
    uint32_t r = 0x7FFFu + ((v.u >> 16) & 1u);
    return (unsigned short)((v.u + r) >> 16);
}

__device__ __forceinline__ bf16x8 cvt8(float4 lo, float4 hi) {
    bf16x8 r;
    r[0] = (short)f32_to_bf16(lo.x); r[1] = (short)f32_to_bf16(lo.y);
    r[2] = (short)f32_to_bf16(lo.z); r[3] = (short)f32_to_bf16(lo.w);
    r[4] = (short)f32_to_bf16(hi.x); r[5] = (short)f32_to_bf16(hi.y);
    r[6] = (short)f32_to_bf16(hi.z); r[7] = (short)f32_to_bf16(hi.w);
    return r;
}

__device__ __forceinline__ void gload16(const void* src, void* lds) {
    __builtin_amdgcn_global_load_lds(
        (const __attribute__((address_space(1))) void*)src,
        (__attribute__((address_space(3))) void*)lds, 16, 0, 0);
}

// ---------------- W pre-convert (FROZEN, passing) ----------------
__global__ __launch_bounds__(256)
void wconv_kernel(const float* __restrict__ Wq, const float* __restrict__ Wk,
                  const float* __restrict__ Wv, unsigned short* __restrict__ Wt)
{
    const int t  = blockIdx.x * 256 + threadIdx.x;
    const int n  = t & 127;
    const int kc = (t >> 7) & 127;
    const int p  = t >> 14;
    const float* __restrict__ W = (p == 0) ? Wq : (p == 1) ? Wk : Wv;
    const float sc = (p == 0) ? (1.44269504088896f * 0.0883883476483184f) : 1.0f;
    const float4* src = reinterpret_cast<const float4*>(W + (size_t)n * D_IN + kc * 8);
    float4 a = src[0], b = src[1];
    uint4 o;
    o.x = (uint32_t)f32_to_bf16(a.x * sc) | ((uint32_t)f32_to_bf16(a.y * sc) << 16);
    o.y = (uint32_t)f32_to_bf16(a.z * sc) | ((uint32_t)f32_to_bf16(a.w * sc) << 16);
    o.z = (uint32_t)f32_to_bf16(b.x * sc) | ((uint32_t)f32_to_bf16(b.y * sc) << 16);
    o.w = (uint32_t)f32_to_bf16(b.z * sc) | ((uint32_t)f32_to_bf16(b.w * sc) << 16);
    *reinterpret_cast<uint4*>(Wt + (size_t)t * 8) = o;
}

// ---------------- projection GEMM v15: gload_lds dbuf A staging ------------
// v14's k-loop/B-path/epilogue kept; A staging switched to fire-and-forget
// global_load_lds double-buffer (the R10-attn mechanism): whole-quarter B
// loaded FIRST (bb[16], FIFO-older), then 8 gload_lds prefetch quarter kk+1,
// which stay in flight through the k-loop and drain at the quarter barrier.
// Source pre-swizzled (rule #21); read side byte-identical to v14.
#define RBM 32

__global__ __launch_bounds__(256, 2)
void proj_kernel(const float* __restrict__ Xq, const float* __restrict__ Xk,
                 const float* __restrict__ Xv,
                 const unsigned short* __restrict__ Wt,
                 unsigned short* __restrict__ qh, unsigned short* __restrict__ kh,
                 unsigned short* __restrict__ vhT)
{
    const int p = blockIdx.y;
    const float* __restrict__ X = (p == 0) ? Xq : (p == 1) ? Xk : Xv;
    const unsigned short* __restrict__ Wtp = Wt + (size_t)p * 128 * 128 * 8;

    __shared__ float Asf[2][RBM * 256];   // 2 x 32KB, [row][1KB], src-swizzled

    const int tid  = threadIdx.x;
    const int lane = tid & 63;
    const int w    = tid >> 6;           // wave = column group (32 cols)
    const int lrow = lane & 15;
    const int g    = lane >> 4;
    const int wbase = blockIdx.x * RBM;
    const char* __restrict__ Xb = reinterpret_cast<const char*>(X);

    f32x4 acc[2][2];
    #pragma unroll
    for (int mi = 0; mi < 2; ++mi)
        #pragma unroll
        for (int ni = 0; ni < 2; ++ni)
            acc[mi][ni] = (f32x4){0.f, 0.f, 0.f, 0.f};

    const int aswz = (lrow & 7) << 5;
    bf16x8 bb[16];   // bb[t*2+ni], t=0..7 — all indices static (rule #20)

    // STAGE_A(buf, kk): 8 rows/wave; per-lane global src pre-swizzled
    // (bits 5-7), LDS dest linear (wave-uniform base + lane*16).
    #define STAGE_A(buf, kk_)                                                 \
    do {                                                                      \
        _Pragma("unroll")                                                     \
        for (int i = 0; i < 8; ++i) {                                         \
            const int r_ = w * 8 + i;                                         \
            gload16(Xb + (size_t)(wbase + r_) * 4096 + (kk_) * 1024 +         \
                        ((lane * 16) ^ ((r_ & 7) << 5)),                      \
                    reinterpret_cast<char*>(Asf[buf]) + r_ * 1024);           \
        }                                                                     \
    } while (0)

    STAGE_A(0, 0);
    asm volatile("s_waitcnt vmcnt(0)" ::: "memory");
    __syncthreads();

    int buf = 0;
    #pragma unroll
    for (int kk = 0; kk < 4; ++kk) {
        // whole-quarter B first (FIFO-older than the prefetch gloads)
        const unsigned short* __restrict__ wbk =
            Wtp + ((size_t)(kk * 32 + g) * 128 + w * 32 + lrow) * 8;
        #pragma unroll
        for (int t = 0; t < 8; ++t)
            #pragma unroll
            for (int ni = 0; ni < 2; ++ni)
                bb[t * 2 + ni] = *reinterpret_cast<const bf16x8*>(
                    wbk + ((size_t)(t * 4) * 128 + ni * 16) * 8);

        // prefetch next quarter (fire-and-forget; drains at the barrier)
        if (kk < 3) STAGE_A(buf ^ 1, kk + 1);

        // k-loop: 8 k-steps, all A from LDS (cvt at read), B in regs
        const char* const base = reinterpret_cast<const char*>(Asf[buf]);
        const char* const a0 = base + lrow * 1024;
        const char* const a1 = base + (16 + lrow) * 1024;
        #pragma unroll
        for (int t = 0; t < 8; ++t) {
            const int boff = (t * 128 + g * 32) ^ aswz;
            float4 lo0 = *reinterpret_cast<const float4*>(a0 + boff);
            float4 hi0 = *reinterpret_cast<const float4*>(a0 + boff + 16);
            float4 lo1 = *reinterpret_cast<const float4*>(a1 + boff);
            float4 hi1 = *reinterpret_cast<const float4*>(a1 + boff + 16);
            bf16x8 af0 = cvt8(lo0, hi0);
            bf16x8 af1 = cvt8(lo1, hi1);
            acc[0][0] = __builtin_amdgcn_mfma_f32_16x16x32_bf16(af0, bb[t * 2 + 0], acc[0][0], 0, 0, 0);
            acc[0][1] = __builtin_amdgcn_mfma_f32_16x16x32_bf16(af0, bb[t * 2 + 1], acc[0][1], 0, 0, 0);
            acc[1][0] = __builtin_amdgcn_mfma_f32_16x16x32_bf16(af1, bb[t * 2 + 0], acc[1][0], 0, 0, 0);
            acc[1][1] = __builtin_amdgcn_mfma_f32_16x16x32_bf16(af1, bb[t * 2 + 1], acc[1][1], 0, 0, 0);
        }

        if (kk < 3) {
            __syncthreads();   // drains prefetch into Asf[buf^1]; swap
            buf ^= 1;
        }
    }
    #undef STAGE_A

    // ---- epilogue (v14-proven): col = w*32+ni*16+lrow, row = wbase+mi*16+g*4+r
    if (p < 2) {
        unsigned short* __restrict__ Y = (p == 0) ? qh : kh;
        #pragma unroll
        for (int mi = 0; mi < 2; ++mi) {
            const int rbase = wbase + mi * 16 + g * 4;
            #pragma unroll
            for (int ni = 0; ni < 2; ++ni) {
                const int n = w * 32 + ni * 16 + lrow;
                #pragma unroll
                for (int r = 0; r < 4; ++r)
                    Y[(size_t)(rbase + r) * D_K + n] = f32_to_bf16(acc[mi][ni][r]);
            }
        }
    } else {
        const int b = wbase >> 12;
        #pragma unroll
        for (int mi = 0; mi < 2; ++mi) {
            const int s = (wbase & 4095) + mi * 16 + g * 4;
            #pragma unroll
            for (int ni = 0; ni < 2; ++ni) {
                const int d = w * 32 + ni * 16 + lrow;
                uint2 t;
                t.x = (uint32_t)f32_to_bf16(acc[mi][ni][0]) |
                      ((uint32_t)f32_to_bf16(acc[mi][ni][1]) << 16);
                t.y = (uint32_t)f32_to_bf16(acc[mi][ni][2]) |
                      ((uint32_t)f32_to_bf16(acc[mi][ni][3]) << 16);
                *reinterpret_cast<uint2*>(vhT + ((size_t)(b * D_K + d) << 12) + s) = t;
            }
        }
    }
}

// ---------------- flash attention v11 (FROZEN, passing) --------------------
#define KVB 64
#define PSTRIDE 144

__global__ __launch_bounds__(256, 2)
void attn_kernel(const unsigned short* __restrict__ qh,
                 const unsigned short* __restrict__ kh,
                 const unsigned short* __restrict__ vhT,
                 float* __restrict__ out)
{
    __shared__ unsigned short Ks[2][KVB * D_K];   // 2 x 16KB
    __shared__ unsigned short Vs[2][D_K * KVB];   // 2 x 16KB (V^T)
    __shared__ char Ps[4][16 * PSTRIDE];          // per-wave [16 rows][144B]

    const int tid  = threadIdx.x;
    const int lane = tid & 63;
    const int wave = tid >> 6;
    const int b    = blockIdx.x & 7;     // batch -> XCD L2 locality
    const int qt   = blockIdx.x >> 3;
    const int q0   = qt * 64 + wave * 16;
    const int lrow = lane & 15;
    const int g    = lane >> 4;
    const int g4   = g << 2;
    const int lk16 = g * 16;

    const unsigned short* __restrict__ Kb = kh + (size_t)b * SEQ * D_K;
    const unsigned short* __restrict__ Vb = vhT + (size_t)b * D_K * SEQ;
    char* const Pw = Ps[wave];

    const int kr0  = lane >> 4;
    const int kcbp = (lane & 15) * 16;
    const int vr0  = lane >> 3;
    const int vcbp = (lane & 7) * 16;

    #define STAGE(buf, it_)                                                   \
    do {                                                                      \
        const int s0_ = (it_) * KVB;                                          \
        _Pragma("unroll")                                                     \
        for (int j = 0; j < 4; ++j) {                                         \
            const int blk  = wave * 4 + j;                                    \
            const int krow = blk * 4 + kr0;                                   \
            gload16(reinterpret_cast<const char*>(Kb) +                       \
                        (size_t)(s0_ + krow) * 256 +                          \
                        (kcbp ^ ((krow & 7) << 4)),                           \
                    reinterpret_cast<char*>(Ks[buf]) + blk * 1024);           \
            const int vrow = blk * 8 + vr0;                                   \
            gload16(reinterpret_cast<const char*>(Vb) +                       \
                        (size_t)vrow * (SEQ * 2) + (size_t)s0_ * 2 +          \
                        (vcbp ^ ((vrow & 7) << 4)),                           \
                    reinterpret_cast<char*>(Vs[buf]) + blk * 1024);           \
        }                                                                     \
    } while (0)

    bf16x8 qf[4];
    {
        const char* base = reinterpret_cast<const char*>(
            qh + (size_t)(b * SEQ + q0 + lrow) * D_K);
        #pragma unroll
        for (int ks = 0; ks < 4; ++ks)
            qf[ks] = *reinterpret_cast<const bf16x8*>(base + ks * 64 + lk16);
    }

    f32x4 o[8];
    #pragma unroll
    for (int df = 0; df < 8; ++df) o[df] = (f32x4){0.f, 0.f, 0.f, 0.f};
    float lsum = 0.f;

    STAGE(0, 0);
    asm volatile("s_waitcnt vmcnt(0)" ::: "memory");
    __syncthreads();

    int cur = 0;
    for (int it = 0; it < SEQ / KVB; ++it) {
        if (it + 1 < SEQ / KVB) STAGE(cur ^ 1, it + 1);

        // QK^T swapped: scT[sf][r] = S[q=lrow][kv = sf*16 + 4g + r]
        f32x4 scT[4];
        #pragma unroll
        for (int sf = 0; sf < 4; ++sf) scT[sf] = (f32x4){0.f, 0.f, 0.f, 0.f};
        #pragma unroll
        for (int ks = 0; ks < 4; ++ks) {
            #pragma unroll
            for (int sf = 0; sf < 4; ++sf) {
                const int row = sf * 16 + lrow;
                bf16x8 kf = *reinterpret_cast<const bf16x8*>(
                    reinterpret_cast<const char*>(Ks[cur]) + row * 256 +
                    ((ks * 64 + lk16) ^ ((row & 7) << 4)));
                scT[sf] = __builtin_amdgcn_mfma_f32_16x16x32_bf16(kf, qf[ks], scT[sf], 0, 0, 0);
            }
        }

        #pragma unroll
        for (int sf = 0; sf < 4; ++sf) {
            float p0 = exp2f(scT[sf][0]);
            float p1 = exp2f(scT[sf][1]);
            float p2 = exp2f(scT[sf][2]);
            float p3 = exp2f(scT[sf][3]);
            lsum += (p0 + p1) + (p2 + p3);
            uint32_t u0, u1;
            asm("v_cvt_pk_bf16_f32 %0, %1, %2" : "=v"(u0) : "v"(p0), "v"(p1));
            asm("v_cvt_pk_bf16_f32 %0, %1, %2" : "=v"(u1) : "v"(p2), "v"(p3));
            uint2 t; t.x = u0; t.y = u1;
            *reinterpret_cast<uint2*>(Pw + lrow * PSTRIDE + (4 * sf + g) * 8) = t;
        }

        #pragma unroll
        for (int ks = 0; ks < 2; ++ks) {
            bf16x8 pf = *reinterpret_cast<const bf16x8*>(
                Pw + lrow * PSTRIDE + ks * 64 + g * 16);
            #pragma unroll
            for (int df = 0; df < 8; ++df) {
                const int vr = df * 16 + lrow;
                bf16x8 vf = *reinterpret_cast<const bf16x8*>(
                    reinterpret_cast<const char*>(Vs[cur]) + vr * 128 +
                    ((ks * 64 + lk16) ^ ((vr & 7) << 4)));
                o[df] = __builtin_amdgcn_mfma_f32_16x16x32_bf16(pf, vf, o[df], 0, 0, 0);
            }
        }

        asm volatile("s_waitcnt vmcnt(0)" ::: "memory");
        __syncthreads();
        cur ^= 1;
    }
    #undef STAGE

    float s = lsum;
    s += __shfl_xor(s, 16);
    s += __shfl_xor(s, 32);
    #pragma unroll
    for (int r = 0; r < 4; ++r) {
        float inv = 1.0f / __shfl(s, g4 + r);
        const int row = q0 + g4 + r;
        float* ob = out + (size_t)(b * SEQ + row) * D_K + lrow;
        #pragma unroll
        for (int df = 0; df < 8; ++df)
            ob[df * 16] = o[df][r] * inv;
    }
}

extern "C" void kernel_launch(void* const* d_in, const int* in_sizes, int n_in,
                              void* d_out, int out_size, void* d_ws, size_t ws_size,
                              hipStream_t stream)
{
    (void)in_sizes; (void)n_in; (void)out_size; (void)ws_size;
    const float* q  = (const float*)d_in[0];
    const float* k  = (const float*)d_in[1];
    const float* v  = (const float*)d_in[2];
    const float* Wq = (const float*)d_in[3];
    const float* Wk = (const float*)d_in[4];
    const float* Wv = (const float*)d_in[5];

    unsigned short* qh  = (unsigned short*)d_ws;                 // [32768][128] bf16
    unsigned short* kh  = qh + (size_t)MROWS * D_K;              // [32768][128] bf16
    unsigned short* vhT = kh + (size_t)MROWS * D_K;              // [8][128][4096] bf16
    unsigned short* Wt  = vhT + (size_t)MROWS * D_K;             // [3][128][128][8] bf16

    wconv_kernel<<<dim3(192), 256, 0, stream>>>(Wq, Wk, Wv, Wt);
    proj_kernel<<<dim3(MROWS / RBM, 3), 256, 0, stream>>>(q, k, v, Wt, qh, kh, vhT);
    attn_kernel<<<dim3(NBATCH * (SEQ / 64)), 256, 0, stream>>>(qh, kh, vhT, (float*)d_out);
}

// Round 17
// 209.186 us; speedup vs baseline: 1.1232x; 1.1232x over previous
//
#include <hip/hip_runtime.h>
#include <hip/hip_bf16.h>
#include <stdint.h>

#define D_IN 1024
#define D_K  128
#define NBATCH 8
#define SEQ  4096
#define MROWS (NBATCH * SEQ)

typedef __attribute__((ext_vector_type(8))) short bf16x8;
typedef __attribute__((ext_vector_type(4))) float f32x4;

__device__ __forceinline__ unsigned short f32_to_bf16(float x) {
    union { float f; uint32_t u; } v; v.f = x;
    uint32_t r = 0x7FFFu + ((v.u >> 16) & 1u);
    return (unsigned short)((v.u + r) >> 16);
}

__device__ __forceinline__ bf16x8 cvt8(float4 lo, float4 hi) {
    bf16x8 r;
    r[0] = (short)f32_to_bf16(lo.x); r[1] = (short)f32_to_bf16(lo.y);
    r[2] = (short)f32_to_bf16(lo.z); r[3] = (short)f32_to_bf16(lo.w);
    r[4] = (short)f32_to_bf16(hi.x); r[5] = (short)f32_to_bf16(hi.y);
    r[6] = (short)f32_to_bf16(hi.z); r[7] = (short)f32_to_bf16(hi.w);
    return r;
}

__device__ __forceinline__ void gload16(const void* src, void* lds) {
    __builtin_amdgcn_global_load_lds(
        (const __attribute__((address_space(1))) void*)src,
        (__attribute__((address_space(3))) void*)lds, 16, 0, 0);
}

// ---------------- W pre-convert (FROZEN, passing) ----------------
__global__ __launch_bounds__(256)
void wconv_kernel(const float* __restrict__ Wq, const float* __restrict__ Wk,
                  const float* __restrict__ Wv, unsigned short* __restrict__ Wt)
{
    const int t  = blockIdx.x * 256 + threadIdx.x;
    const int n  = t & 127;
    const int kc = (t >> 7) & 127;
    const int p  = t >> 14;
    const float* __restrict__ W = (p == 0) ? Wq : (p == 1) ? Wk : Wv;
    const float sc = (p == 0) ? (1.44269504088896f * 0.0883883476483184f) : 1.0f;
    const float4* src = reinterpret_cast<const float4*>(W + (size_t)n * D_IN + kc * 8);
    float4 a = src[0], b = src[1];
    uint4 o;
    o.x = (uint32_t)f32_to_bf16(a.x * sc) | ((uint32_t)f32_to_bf16(a.y * sc) << 16);
    o.y = (uint32_t)f32_to_bf16(a.z * sc) | ((uint32_t)f32_to_bf16(a.w * sc) << 16);
    o.z = (uint32_t)f32_to_bf16(b.x * sc) | ((uint32_t)f32_to_bf16(b.y * sc) << 16);
    o.w = (uint32_t)f32_to_bf16(b.z * sc) | ((uint32_t)f32_to_bf16(b.w * sc) << 16);
    *reinterpret_cast<uint4*>(Wt + (size_t)t * 8) = o;
}

// ---------------- projection GEMM v16: eighth-K deep pipeline --------------
// v14 k-loop math kept (column-split waves, B-in-regs, same epilogue).
// A staging: 8 eighth-K tiles [32][128 f32] (16KB), 3 LDS buffers (48KB ->
// 3 blocks/CU), depth-2 gload_lds prefetch with RAW s_barrier + counted
// s_waitcnt vmcnt(12) (T3+T4: loads stay in flight across barriers; never
// drain to 0 in the main loop). Source pre-swizzled (rule #21).
#define RBM 32

__global__ __launch_bounds__(256, 3)
void proj_kernel(const float* __restrict__ Xq, const float* __restrict__ Xk,
                 const float* __restrict__ Xv,
                 const unsigned short* __restrict__ Wt,
                 unsigned short* __restrict__ qh, unsigned short* __restrict__ kh,
                 unsigned short* __restrict__ vhT)
{
    const int p = blockIdx.y;
    const float* __restrict__ X = (p == 0) ? Xq : (p == 1) ? Xk : Xv;
    const unsigned short* __restrict__ Wtp = Wt + (size_t)p * 128 * 128 * 8;

    __shared__ char As8[3 * 16384];   // 3 x [32 rows][512B], src-swizzled

    const int tid  = threadIdx.x;
    const int lane = tid & 63;
    const int w    = tid >> 6;           // wave = column group (32 cols)
    const int lrow = lane & 15;
    const int g    = lane >> 4;
    const int wbase = blockIdx.x * RBM;
    const char* __restrict__ Xb = reinterpret_cast<const char*>(X);

    f32x4 acc[2][2];
    #pragma unroll
    for (int mi = 0; mi < 2; ++mi)
        #pragma unroll
        for (int ni = 0; ni < 2; ++ni)
            acc[mi][ni] = (f32x4){0.f, 0.f, 0.f, 0.f};

    // read-side swizzle (bits 4-6 of byte offset within the 512B row)
    const int swzr = ((lrow & 3) << 5) | (((lrow >> 2) & 1) << 4);
    bf16x8 bb0[8], bb1[8];   // per-eighth B, double-buffered by unroll parity

    // STAGE_A8(buf, e): 4 gloads/wave; each loads 2 rows (lanes 0-31 / 32-63),
    // LDS dest linear, global source pre-swizzled with the same involution.
    #define STAGE_A8(buf_, e_)                                                \
    do {                                                                      \
        _Pragma("unroll")                                                     \
        for (int j = 0; j < 4; ++j) {                                         \
            const int rr   = w * 8 + 2 * j + (lane >> 5);                     \
            const int swzb = ((rr & 3) << 5) | (((rr >> 2) & 1) << 4);        \
            gload16(Xb + (size_t)(wbase + rr) * 4096 + (e_) * 512 +           \
                        (((lane & 31) * 16) ^ swzb),                          \
                    As8 + (buf_) * 16384 + (w * 8 + 2 * j) * 512);            \
        }                                                                     \
    } while (0)

    #define LOAD_BB(dst_, e_)                                                 \
    do {                                                                      \
        _Pragma("unroll")                                                     \
        for (int t = 0; t < 4; ++t)                                           \
            _Pragma("unroll")                                                 \
            for (int ni = 0; ni < 2; ++ni)                                    \
                dst_[t * 2 + ni] = *reinterpret_cast<const bf16x8*>(          \
                    Wtp + ((size_t)(16 * (e_) + 4 * t + g) * 128 +            \
                           w * 32 + ni * 16 + lrow) * 8);                     \
    } while (0)

    // prologue: A(0), A(1), bb(0)
    STAGE_A8(0, 0);
    STAGE_A8(1, 1);
    LOAD_BB(bb0, 0);

    #pragma unroll
    for (int e = 0; e < 8; ++e) {
        __builtin_amdgcn_s_barrier();          // raw: no vmcnt drain
        if (e + 2 < 8) STAGE_A8((e + 2) % 3, e + 2);
        if (e + 1 < 8) {
            if ((e & 1) == 0) LOAD_BB(bb1, e + 1);
            else              LOAD_BB(bb0, e + 1);
        }
        // wait for bb(e) (and, by FIFO order, A(e)); leave the 12 younger
        // ops (A(e+2): 4 gloads, bb(e+1): 8 loads) in flight.
        if (e <= 5)      asm volatile("s_waitcnt vmcnt(12)" ::: "memory");
        else if (e == 6) asm volatile("s_waitcnt vmcnt(8)"  ::: "memory");
        else             asm volatile("s_waitcnt vmcnt(0)"  ::: "memory");

        const char* const bufb = As8 + (e % 3) * 16384;
        const char* const a0 = bufb + lrow * 512;
        const char* const a1 = bufb + (16 + lrow) * 512;  // same swzr (row&3, bit2 parity match)
        #pragma unroll
        for (int t = 0; t < 4; ++t) {
            const int ob = t * 128 + g * 32;
            float4 lo0 = *reinterpret_cast<const float4*>(a0 + (ob ^ swzr));
            float4 hi0 = *reinterpret_cast<const float4*>(a0 + ((ob + 16) ^ swzr));
            float4 lo1 = *reinterpret_cast<const float4*>(a1 + (ob ^ swzr));
            float4 hi1 = *reinterpret_cast<const float4*>(a1 + ((ob + 16) ^ swzr));
            bf16x8 af0 = cvt8(lo0, hi0);
            bf16x8 af1 = cvt8(lo1, hi1);
            const bf16x8* bc = ((e & 1) == 0) ? bb0 : bb1;
            acc[0][0] = __builtin_amdgcn_mfma_f32_16x16x32_bf16(af0, bc[t * 2 + 0], acc[0][0], 0, 0, 0);
            acc[0][1] = __builtin_amdgcn_mfma_f32_16x16x32_bf16(af0, bc[t * 2 + 1], acc[0][1], 0, 0, 0);
            acc[1][0] = __builtin_amdgcn_mfma_f32_16x16x32_bf16(af1, bc[t * 2 + 0], acc[1][0], 0, 0, 0);
            acc[1][1] = __builtin_amdgcn_mfma_f32_16x16x32_bf16(af1, bc[t * 2 + 1], acc[1][1], 0, 0, 0);
        }
    }
    #undef STAGE_A8
    #undef LOAD_BB

    // ---- epilogue (v14-proven): col = w*32+ni*16+lrow, row = wbase+mi*16+g*4+r
    if (p < 2) {
        unsigned short* __restrict__ Y = (p == 0) ? qh : kh;
        #pragma unroll
        for (int mi = 0; mi < 2; ++mi) {
            const int rbase = wbase + mi * 16 + g * 4;
            #pragma unroll
            for (int ni = 0; ni < 2; ++ni) {
                const int n = w * 32 + ni * 16 + lrow;
                #pragma unroll
                for (int r = 0; r < 4; ++r)
                    Y[(size_t)(rbase + r) * D_K + n] = f32_to_bf16(acc[mi][ni][r]);
            }
        }
    } else {
        const int b = wbase >> 12;
        #pragma unroll
        for (int mi = 0; mi < 2; ++mi) {
            const int s = (wbase & 4095) + mi * 16 + g * 4;
            #pragma unroll
            for (int ni = 0; ni < 2; ++ni) {
                const int d = w * 32 + ni * 16 + lrow;
                uint2 t;
                t.x = (uint32_t)f32_to_bf16(acc[mi][ni][0]) |
                      ((uint32_t)f32_to_bf16(acc[mi][ni][1]) << 16);
                t.y = (uint32_t)f32_to_bf16(acc[mi][ni][2]) |
                      ((uint32_t)f32_to_bf16(acc[mi][ni][3]) << 16);
                *reinterpret_cast<uint2*>(vhT + ((size_t)(b * D_K + d) << 12) + s) = t;
            }
        }
    }
}

// ---------------- flash attention v11 (FROZEN, passing) --------------------
#define KVB 64
#define PSTRIDE 144

__global__ __launch_bounds__(256, 2)
void attn_kernel(const unsigned short* __restrict__ qh,
                 const unsigned short* __restrict__ kh,
                 const unsigned short* __restrict__ vhT,
                 float* __restrict__ out)
{
    __shared__ unsigned short Ks[2][KVB * D_K];   // 2 x 16KB
    __shared__ unsigned short Vs[2][D_K * KVB];   // 2 x 16KB (V^T)
    __shared__ char Ps[4][16 * PSTRIDE];          // per-wave [16 rows][144B]

    const int tid  = threadIdx.x;
    const int lane = tid & 63;
    const int wave = tid >> 6;
    const int b    = blockIdx.x & 7;     // batch -> XCD L2 locality
    const int qt   = blockIdx.x >> 3;
    const int q0   = qt * 64 + wave * 16;
    const int lrow = lane & 15;
    const int g    = lane >> 4;
    const int g4   = g << 2;
    const int lk16 = g * 16;

    const unsigned short* __restrict__ Kb = kh + (size_t)b * SEQ * D_K;
    const unsigned short* __restrict__ Vb = vhT + (size_t)b * D_K * SEQ;
    char* const Pw = Ps[wave];

    const int kr0  = lane >> 4;
    const int kcbp = (lane & 15) * 16;
    const int vr0  = lane >> 3;
    const int vcbp = (lane & 7) * 16;

    #define STAGE(buf, it_)                                                   \
    do {                                                                      \
        const int s0_ = (it_) * KVB;                                          \
        _Pragma("unroll")                                                     \
        for (int j = 0; j < 4; ++j) {                                         \
            const int blk  = wave * 4 + j;                                    \
            const int krow = blk * 4 + kr0;                                   \
            gload16(reinterpret_cast<const char*>(Kb) +                       \
                        (size_t)(s0_ + krow) * 256 +                          \
                        (kcbp ^ ((krow & 7) << 4)),                           \
                    reinterpret_cast<char*>(Ks[buf]) + blk * 1024);           \
            const int vrow = blk * 8 + vr0;                                   \
            gload16(reinterpret_cast<const char*>(Vb) +                       \
                        (size_t)vrow * (SEQ * 2) + (size_t)s0_ * 2 +          \
                        (vcbp ^ ((vrow & 7) << 4)),                           \
                    reinterpret_cast<char*>(Vs[buf]) + blk * 1024);           \
        }                                                                     \
    } while (0)

    bf16x8 qf[4];
    {
        const char* base = reinterpret_cast<const char*>(
            qh + (size_t)(b * SEQ + q0 + lrow) * D_K);
        #pragma unroll
        for (int ks = 0; ks < 4; ++ks)
            qf[ks] = *reinterpret_cast<const bf16x8*>(base + ks * 64 + lk16);
    }

    f32x4 o[8];
    #pragma unroll
    for (int df = 0; df < 8; ++df) o[df] = (f32x4){0.f, 0.f, 0.f, 0.f};
    float lsum = 0.f;

    STAGE(0, 0);
    asm volatile("s_waitcnt vmcnt(0)" ::: "memory");
    __syncthreads();

    int cur = 0;
    for (int it = 0; it < SEQ / KVB; ++it) {
        if (it + 1 < SEQ / KVB) STAGE(cur ^ 1, it + 1);

        f32x4 scT[4];
        #pragma unroll
        for (int sf = 0; sf < 4; ++sf) scT[sf] = (f32x4){0.f, 0.f, 0.f, 0.f};
        #pragma unroll
        for (int ks = 0; ks < 4; ++ks) {
            #pragma unroll
            for (int sf = 0; sf < 4; ++sf) {
                const int row = sf * 16 + lrow;
                bf16x8 kf = *reinterpret_cast<const bf16x8*>(
                    reinterpret_cast<const char*>(Ks[cur]) + row * 256 +
                    ((ks * 64 + lk16) ^ ((row & 7) << 4)));
                scT[sf] = __builtin_amdgcn_mfma_f32_16x16x32_bf16(kf, qf[ks], scT[sf], 0, 0, 0);
            }
        }

        #pragma unroll
        for (int sf = 0; sf < 4; ++sf) {
            float p0 = exp2f(scT[sf][0]);
            float p1 = exp2f(scT[sf][1]);
            float p2 = exp2f(scT[sf][2]);
            float p3 = exp2f(scT[sf][3]);
            lsum += (p0 + p1) + (p2 + p3);
            uint32_t u0, u1;
            asm("v_cvt_pk_bf16_f32 %0, %1, %2" : "=v"(u0) : "v"(p0), "v"(p1));
            asm("v_cvt_pk_bf16_f32 %0, %1, %2" : "=v"(u1) : "v"(p2), "v"(p3));
            uint2 t; t.x = u0; t.y = u1;
            *reinterpret_cast<uint2*>(Pw + lrow * PSTRIDE + (4 * sf + g) * 8) = t;
        }

        #pragma unroll
        for (int ks = 0; ks < 2; ++ks) {
            bf16x8 pf = *reinterpret_cast<const bf16x8*>(
                Pw + lrow * PSTRIDE + ks * 64 + g * 16);
            #pragma unroll
            for (int df = 0; df < 8; ++df) {
                const int vr = df * 16 + lrow;
                bf16x8 vf = *reinterpret_cast<const bf16x8*>(
                    reinterpret_cast<const char*>(Vs[cur]) + vr * 128 +
                    ((ks * 64 + lk16) ^ ((vr & 7) << 4)));
                o[df] = __builtin_amdgcn_mfma_f32_16x16x32_bf16(pf, vf, o[df], 0, 0, 0);
            }
        }

        asm volatile("s_waitcnt vmcnt(0)" ::: "memory");
        __syncthreads();
        cur ^= 1;
    }
    #undef STAGE

    float s = lsum;
    s += __shfl_xor(s, 16);
    s += __shfl_xor(s, 32);
    #pragma unroll
    for (int r = 0; r < 4; ++r) {
        float inv = 1.0f / __shfl(s, g4 + r);
        const int row = q0 + g4 + r;
        float* ob = out + (size_t)(b * SEQ + row) * D_K + lrow;
        #pragma unroll
        for (int df = 0; df < 8; ++df)
            ob[df * 16] = o[df][r] * inv;
    }
}

extern "C" void kernel_launch(void* const* d_in, const int* in_sizes, int n_in,
                              void* d_out, int out_size, void* d_ws, size_t ws_size,
                              hipStream_t stream)
{
    (void)in_sizes; (void)n_in; (void)out_size; (void)ws_size;
    const float* q  = (const float*)d_in[0];
    const float* k  = (const float*)d_in[1];
    const float* v  = (const float*)d_in[2];
    const float* Wq = (const float*)d_in[3];
    const float* Wk = (const float*)d_in[4];
    const float* Wv = (const float*)d_in[5];

    unsigned short* qh  = (unsigned short*)d_ws;                 // [32768][128] bf16
    unsigned short* kh  = qh + (size_t)MROWS * D_K;              // [32768][128] bf16
    unsigned short* vhT = kh + (size_t)MROWS * D_K;              // [8][128][4096] bf16
    unsigned short* Wt  = vhT + (size_t)MROWS * D_K;             // [3][128][128][8] bf16

    wconv_kernel<<<dim3(192), 256, 0, stream>>>(Wq, Wk, Wv, Wt);
    proj_kernel<<<dim3(MROWS / RBM, 3), 256, 0, stream>>>(q, k, v, Wt, qh, kh, vhT);
    attn_kernel<<<dim3(NBATCH * (SEQ / 64)), 256, 0, stream>>>(qh, kh, vhT, (float*)d_out);
}

// Round 18
// 206.806 us; speedup vs baseline: 1.1362x; 1.0115x over previous
//
#include <hip/hip_runtime.h>
#include <hip/hip_bf16.h>
#include <stdint.h>

#define D_IN 1024
#define D_K  128
#define NBATCH 8
#define SEQ  4096
#define MROWS (NBATCH * SEQ)

typedef __attribute__((ext_vector_type(8))) short bf16x8;
typedef __attribute__((ext_vector_type(4))) float f32x4;

__device__ __forceinline__ unsigned short f32_to_bf16(float x) {
    union { float f; uint32_t u; } v; v.f = x;
    uint32_t r = 0x7FFFu + ((v.u >> 16) & 1u);
    return (unsigned short)((v.u + r) >> 16);
}

__device__ __forceinline__ bf16x8 cvt8(float4 lo, float4 hi) {
    bf16x8 r;
    r[0] = (short)f32_to_bf16(lo.x); r[1] = (short)f32_to_bf16(lo.y);
    r[2] = (short)f32_to_bf16(lo.z); r[3] = (short)f32_to_bf16(lo.w);
    r[4] = (short)f32_to_bf16(hi.x); r[5] = (short)f32_to_bf16(hi.y);
    r[6] = (short)f32_to_bf16(hi.z); r[7] = (short)f32_to_bf16(hi.w);
    return r;
}

__device__ __forceinline__ void gload16(const void* src, void* lds) {
    __builtin_amdgcn_global_load_lds(
        (const __attribute__((address_space(1))) void*)src,
        (__attribute__((address_space(3))) void*)lds, 16, 0, 0);
}

// ---------------- W pre-convert (FROZEN, passing) ----------------
__global__ __launch_bounds__(256)
void wconv_kernel(const float* __restrict__ Wq, const float* __restrict__ Wk,
                  const float* __restrict__ Wv, unsigned short* __restrict__ Wt)
{
    const int t  = blockIdx.x * 256 + threadIdx.x;
    const int n  = t & 127;
    const int kc = (t >> 7) & 127;
    const int p  = t >> 14;
    const float* __restrict__ W = (p == 0) ? Wq : (p == 1) ? Wk : Wv;
    const float sc = (p == 0) ? (1.44269504088896f * 0.0883883476483184f) : 1.0f;
    const float4* src = reinterpret_cast<const float4*>(W + (size_t)n * D_IN + kc * 8);
    float4 a = src[0], b = src[1];
    uint4 o;
    o.x = (uint32_t)f32_to_bf16(a.x * sc) | ((uint32_t)f32_to_bf16(a.y * sc) << 16);
    o.y = (uint32_t)f32_to_bf16(a.z * sc) | ((uint32_t)f32_to_bf16(a.w * sc) << 16);
    o.z = (uint32_t)f32_to_bf16(b.x * sc) | ((uint32_t)f32_to_bf16(b.y * sc) << 16);
    o.w = (uint32_t)f32_to_bf16(b.z * sc) | ((uint32_t)f32_to_bf16(b.w * sc) << 16);
    *reinterpret_cast<uint4*>(Wt + (size_t)t * 8) = o;
}

// ---------------- projection GEMM v17: FIFO-decoupled deep pipeline --------
// v16 body, but: (1) bb(e+1) issued BEFORE A(e+2) each iter, so the counted
// wait for bb(e) does NOT drain A(e+1) -- A keeps a true 2-iteration cover;
// (2) two raw barriers/iter (WAR close + post-drain publish) make cross-wave
// LDS visibility correct without vmcnt(0). Steady wait: vmcnt(16).
#define RBM 32

__global__ __launch_bounds__(256, 3)
void proj_kernel(const float* __restrict__ Xq, const float* __restrict__ Xk,
                 const float* __restrict__ Xv,
                 const unsigned short* __restrict__ Wt,
                 unsigned short* __restrict__ qh, unsigned short* __restrict__ kh,
                 unsigned short* __restrict__ vhT)
{
    const int p = blockIdx.y;
    const float* __restrict__ X = (p == 0) ? Xq : (p == 1) ? Xk : Xv;
    const unsigned short* __restrict__ Wtp = Wt + (size_t)p * 128 * 128 * 8;

    __shared__ char As8[3 * 16384];   // 3 x [32 rows][512B], src-swizzled

    const int tid  = threadIdx.x;
    const int lane = tid & 63;
    const int w    = tid >> 6;           // wave = column group (32 cols)
    const int lrow = lane & 15;
    const int g    = lane >> 4;
    const int wbase = blockIdx.x * RBM;
    const char* __restrict__ Xb = reinterpret_cast<const char*>(X);

    f32x4 acc[2][2];
    #pragma unroll
    for (int mi = 0; mi < 2; ++mi)
        #pragma unroll
        for (int ni = 0; ni < 2; ++ni)
            acc[mi][ni] = (f32x4){0.f, 0.f, 0.f, 0.f};

    const int swzr = ((lrow & 3) << 5) | (((lrow >> 2) & 1) << 4);
    bf16x8 bb0[8], bb1[8];   // per-eighth B, double-buffered by unroll parity

    #define STAGE_A8(buf_, e_)                                                \
    do {                                                                      \
        _Pragma("unroll")                                                     \
        for (int j = 0; j < 4; ++j) {                                         \
            const int rr   = w * 8 + 2 * j + (lane >> 5);                     \
            const int swzb = ((rr & 3) << 5) | (((rr >> 2) & 1) << 4);        \
            gload16(Xb + (size_t)(wbase + rr) * 4096 + (e_) * 512 +           \
                        (((lane & 31) * 16) ^ swzb),                          \
                    As8 + (buf_) * 16384 + (w * 8 + 2 * j) * 512);            \
        }                                                                     \
    } while (0)

    #define LOAD_BB(dst_, e_)                                                 \
    do {                                                                      \
        _Pragma("unroll")                                                     \
        for (int t = 0; t < 4; ++t)                                           \
            _Pragma("unroll")                                                 \
            for (int ni = 0; ni < 2; ++ni)                                    \
                dst_[t * 2 + ni] = *reinterpret_cast<const bf16x8*>(          \
                    Wtp + ((size_t)(16 * (e_) + 4 * t + g) * 128 +            \
                           w * 32 + ni * 16 + lrow) * 8);                     \
    } while (0)

    // prologue FIFO order is load-bearing: A(0), bb(0), A(1)
    STAGE_A8(0, 0);
    LOAD_BB(bb0, 0);
    STAGE_A8(1, 1);

    #pragma unroll
    for (int e = 0; e < 8; ++e) {
        // close last iter's reads of buf((e-1)%3) == target of A(e+2)  [WAR]
        __builtin_amdgcn_s_barrier();
        // bb(e+1) FIRST (younger FIFO slot goes to A so it survives the wait)
        if (e + 1 < 8) {
            if ((e & 1) == 0) LOAD_BB(bb1, e + 1);
            else              LOAD_BB(bb0, e + 1);
        }
        if (e + 2 < 8) STAGE_A8((e + 2) % 3, e + 2);
        // drain own A(e)+bb(e) (12 ops); A(e+1), bb(e+1), A(e+2) stay in flight
        if (e <= 5)      asm volatile("s_waitcnt vmcnt(16)" ::: "memory");
        else if (e == 6) asm volatile("s_waitcnt vmcnt(12)" ::: "memory");
        else             asm volatile("s_waitcnt vmcnt(0)"  ::: "memory");
        // publish: every wave has drained its own A(e) gloads  [RAW]
        __builtin_amdgcn_s_barrier();

        const char* const bufb = As8 + (e % 3) * 16384;
        const char* const a0 = bufb + lrow * 512;
        const char* const a1 = bufb + (16 + lrow) * 512;
        #pragma unroll
        for (int t = 0; t < 4; ++t) {
            const int ob = t * 128 + g * 32;
            float4 lo0 = *reinterpret_cast<const float4*>(a0 + (ob ^ swzr));
            float4 hi0 = *reinterpret_cast<const float4*>(a0 + ((ob + 16) ^ swzr));
            float4 lo1 = *reinterpret_cast<const float4*>(a1 + (ob ^ swzr));
            float4 hi1 = *reinterpret_cast<const float4*>(a1 + ((ob + 16) ^ swzr));
            bf16x8 af0 = cvt8(lo0, hi0);
            bf16x8 af1 = cvt8(lo1, hi1);
            const bf16x8* bc = ((e & 1) == 0) ? bb0 : bb1;
            acc[0][0] = __builtin_amdgcn_mfma_f32_16x16x32_bf16(af0, bc[t * 2 + 0], acc[0][0], 0, 0, 0);
            acc[0][1] = __builtin_amdgcn_mfma_f32_16x16x32_bf16(af0, bc[t * 2 + 1], acc[0][1], 0, 0, 0);
            acc[1][0] = __builtin_amdgcn_mfma_f32_16x16x32_bf16(af1, bc[t * 2 + 0], acc[1][0], 0, 0, 0);
            acc[1][1] = __builtin_amdgcn_mfma_f32_16x16x32_bf16(af1, bc[t * 2 + 1], acc[1][1], 0, 0, 0);
        }
    }
    #undef STAGE_A8
    #undef LOAD_BB

    // ---- epilogue (v14-proven): col = w*32+ni*16+lrow, row = wbase+mi*16+g*4+r
    if (p < 2) {
        unsigned short* __restrict__ Y = (p == 0) ? qh : kh;
        #pragma unroll
        for (int mi = 0; mi < 2; ++mi) {
            const int rbase = wbase + mi * 16 + g * 4;
            #pragma unroll
            for (int ni = 0; ni < 2; ++ni) {
                const int n = w * 32 + ni * 16 + lrow;
                #pragma unroll
                for (int r = 0; r < 4; ++r)
                    Y[(size_t)(rbase + r) * D_K + n] = f32_to_bf16(acc[mi][ni][r]);
            }
        }
    } else {
        const int b = wbase >> 12;
        #pragma unroll
        for (int mi = 0; mi < 2; ++mi) {
            const int s = (wbase & 4095) + mi * 16 + g * 4;
            #pragma unroll
            for (int ni = 0; ni < 2; ++ni) {
                const int d = w * 32 + ni * 16 + lrow;
                uint2 t;
                t.x = (uint32_t)f32_to_bf16(acc[mi][ni][0]) |
                      ((uint32_t)f32_to_bf16(acc[mi][ni][1]) << 16);
                t.y = (uint32_t)f32_to_bf16(acc[mi][ni][2]) |
                      ((uint32_t)f32_to_bf16(acc[mi][ni][3]) << 16);
                *reinterpret_cast<uint2*>(vhT + ((size_t)(b * D_K + d) << 12) + s) = t;
            }
        }
    }
}

// ---------------- flash attention v11 (FROZEN, passing) --------------------
#define KVB 64
#define PSTRIDE 144

__global__ __launch_bounds__(256, 2)
void attn_kernel(const unsigned short* __restrict__ qh,
                 const unsigned short* __restrict__ kh,
                 const unsigned short* __restrict__ vhT,
                 float* __restrict__ out)
{
    __shared__ unsigned short Ks[2][KVB * D_K];   // 2 x 16KB
    __shared__ unsigned short Vs[2][D_K * KVB];   // 2 x 16KB (V^T)
    __shared__ char Ps[4][16 * PSTRIDE];          // per-wave [16 rows][144B]

    const int tid  = threadIdx.x;
    const int lane = tid & 63;
    const int wave = tid >> 6;
    const int b    = blockIdx.x & 7;     // batch -> XCD L2 locality
    const int qt   = blockIdx.x >> 3;
    const int q0   = qt * 64 + wave * 16;
    const int lrow = lane & 15;
    const int g    = lane >> 4;
    const int g4   = g << 2;
    const int lk16 = g * 16;

    const unsigned short* __restrict__ Kb = kh + (size_t)b * SEQ * D_K;
    const unsigned short* __restrict__ Vb = vhT + (size_t)b * D_K * SEQ;
    char* const Pw = Ps[wave];

    const int kr0  = lane >> 4;
    const int kcbp = (lane & 15) * 16;
    const int vr0  = lane >> 3;
    const int vcbp = (lane & 7) * 16;

    #define STAGE(buf, it_)                                                   \
    do {                                                                      \
        const int s0_ = (it_) * KVB;                                          \
        _Pragma("unroll")                                                     \
        for (int j = 0; j < 4; ++j) {                                         \
            const int blk  = wave * 4 + j;                                    \
            const int krow = blk * 4 + kr0;                                   \
            gload16(reinterpret_cast<const char*>(Kb) +                       \
                        (size_t)(s0_ + krow) * 256 +                          \
                        (kcbp ^ ((krow & 7) << 4)),                           \
                    reinterpret_cast<char*>(Ks[buf]) + blk * 1024);           \
            const int vrow = blk * 8 + vr0;                                   \
            gload16(reinterpret_cast<const char*>(Vb) +                       \
                        (size_t)vrow * (SEQ * 2) + (size_t)s0_ * 2 +          \
                        (vcbp ^ ((vrow & 7) << 4)),                           \
                    reinterpret_cast<char*>(Vs[buf]) + blk * 1024);           \
        }                                                                     \
    } while (0)

    bf16x8 qf[4];
    {
        const char* base = reinterpret_cast<const char*>(
            qh + (size_t)(b * SEQ + q0 + lrow) * D_K);
        #pragma unroll
        for (int ks = 0; ks < 4; ++ks)
            qf[ks] = *reinterpret_cast<const bf16x8*>(base + ks * 64 + lk16);
    }

    f32x4 o[8];
    #pragma unroll
    for (int df = 0; df < 8; ++df) o[df] = (f32x4){0.f, 0.f, 0.f, 0.f};
    float lsum = 0.f;

    STAGE(0, 0);
    asm volatile("s_waitcnt vmcnt(0)" ::: "memory");
    __syncthreads();

    int cur = 0;
    for (int it = 0; it < SEQ / KVB; ++it) {
        if (it + 1 < SEQ / KVB) STAGE(cur ^ 1, it + 1);

        f32x4 scT[4];
        #pragma unroll
        for (int sf = 0; sf < 4; ++sf) scT[sf] = (f32x4){0.f, 0.f, 0.f, 0.f};
        #pragma unroll
        for (int ks = 0; ks < 4; ++ks) {
            #pragma unroll
            for (int sf = 0; sf < 4; ++sf) {
                const int row = sf * 16 + lrow;
                bf16x8 kf = *reinterpret_cast<const bf16x8*>(
                    reinterpret_cast<const char*>(Ks[cur]) + row * 256 +
                    ((ks * 64 + lk16) ^ ((row & 7) << 4)));
                scT[sf] = __builtin_amdgcn_mfma_f32_16x16x32_bf16(kf, qf[ks], scT[sf], 0, 0, 0);
            }
        }

        #pragma unroll
        for (int sf = 0; sf < 4; ++sf) {
            float p0 = exp2f(scT[sf][0]);
            float p1 = exp2f(scT[sf][1]);
            float p2 = exp2f(scT[sf][2]);
            float p3 = exp2f(scT[sf][3]);
            lsum += (p0 + p1) + (p2 + p3);
            uint32_t u0, u1;
            asm("v_cvt_pk_bf16_f32 %0, %1, %2" : "=v"(u0) : "v"(p0), "v"(p1));
            asm("v_cvt_pk_bf16_f32 %0, %1, %2" : "=v"(u1) : "v"(p2), "v"(p3));
            uint2 t; t.x = u0; t.y = u1;
            *reinterpret_cast<uint2*>(Pw + lrow * PSTRIDE + (4 * sf + g) * 8) = t;
        }

        #pragma unroll
        for (int ks = 0; ks < 2; ++ks) {
            bf16x8 pf = *reinterpret_cast<const bf16x8*>(
                Pw + lrow * PSTRIDE + ks * 64 + g * 16);
            #pragma unroll
            for (int df = 0; df < 8; ++df) {
                const int vr = df * 16 + lrow;
                bf16x8 vf = *reinterpret_cast<const bf16x8*>(
                    reinterpret_cast<const char*>(Vs[cur]) + vr * 128 +
                    ((ks * 64 + lk16) ^ ((vr & 7) << 4)));
                o[df] = __builtin_amdgcn_mfma_f32_16x16x32_bf16(pf, vf, o[df], 0, 0, 0);
            }
        }

        asm volatile("s_waitcnt vmcnt(0)" ::: "memory");
        __syncthreads();
        cur ^= 1;
    }
    #undef STAGE

    float s = lsum;
    s += __shfl_xor(s, 16);
    s += __shfl_xor(s, 32);
    #pragma unroll
    for (int r = 0; r < 4; ++r) {
        float inv = 1.0f / __shfl(s, g4 + r);
        const int row = q0 + g4 + r;
        float* ob = out + (size_t)(b * SEQ + row) * D_K + lrow;
        #pragma unroll
        for (int df = 0; df < 8; ++df)
            ob[df * 16] = o[df][r] * inv;
    }
}

extern "C" void kernel_launch(void* const* d_in, const int* in_sizes, int n_in,
                              void* d_out, int out_size, void* d_ws, size_t ws_size,
                              hipStream_t stream)
{
    (void)in_sizes; (void)n_in; (void)out_size; (void)ws_size;
    const float* q  = (const float*)d_in[0];
    const float* k  = (const float*)d_in[1];
    const float* v  = (const float*)d_in[2];
    const float* Wq = (const float*)d_in[3];
    const float* Wk = (const float*)d_in[4];
    const float* Wv = (const float*)d_in[5];

    unsigned short* qh  = (unsigned short*)d_ws;                 // [32768][128] bf16
    unsigned short* kh  = qh + (size_t)MROWS * D_K;              // [32768][128] bf16
    unsigned short* vhT = kh + (size_t)MROWS * D_K;              // [8][128][4096] bf16
    unsigned short* Wt  = vhT + (size_t)MROWS * D_K;             // [3][128][128][8] bf16

    wconv_kernel<<<dim3(192), 256, 0, stream>>>(Wq, Wk, Wv, Wt);
    proj_kernel<<<dim3(MROWS / RBM, 3), 256, 0, stream>>>(q, k, v, Wt, qh, kh, vhT);
    attn_kernel<<<dim3(NBATCH * (SEQ / 64)), 256, 0, stream>>>(qh, kh, vhT, (float*)d_out);
}